// Round 2
// baseline (18666.191 us; speedup 1.0000x reference)
//
#include <hip/hip_runtime.h>
#include <math.h>

#define BB 256   // batch
#define TT 128   // time steps
#define DD 256   // input dim
#define UU 512   // units
#define G5 (5 * UU)   // 2560
#define G4 (4 * UU)   // 2048 (packed width for rk and tk)
#define NBLK 256

__device__ __forceinline__ float hsig(float x) {
    return fminf(fmaxf(0.2f * x + 0.5f, 0.0f), 1.0f);
}

// ---------------------------------------------------------------------------
// Pack weights into gate-interleaved layout: col = u*4 + g   (verified layout)
//   rkp[k][u*4+g]  = rk[k][g*U+u]              (g<4)
//   tkpX[k][u*4+g] = tk[X][k][g*U+u] (g<3), 0  (g==3 pad)
// ---------------------------------------------------------------------------
__global__ __launch_bounds__(256) void pack_weights(
    const float* __restrict__ rk, const float* __restrict__ tk,
    float* __restrict__ rkp, float* __restrict__ tkp0, float* __restrict__ tkp1)
{
    int idx = blockIdx.x * 256 + threadIdx.x;   // 0 .. 512*2048
    int k = idx >> 11;
    int c = idx & 2047;
    int u = c >> 2;
    int g = c & 3;
    rkp[idx] = rk[k * G4 + g * UU + u];
    float t0 = 0.f, t1 = 0.f;
    if (g < 3) {
        t0 = tk[(size_t)k * (3 * UU) + g * UU + u];
        t1 = tk[(size_t)(UU + k) * (3 * UU) + g * UU + u];
    }
    tkp0[idx] = t0;
    tkp1[idx] = t1;
}

// h state kept transposed: hT[u][b]  (u-major) so GEMM A-staging is coalesced
__global__ __launch_bounds__(256) void init_hT(
    const float* __restrict__ h0, float* __restrict__ hT)
{
    int idx = blockIdx.x * 256 + threadIdx.x;   // 0 .. 131071
    int u = idx >> 8;
    int b = idx & 255;
    hT[idx] = h0[(size_t)b * UU + u];
}

// ---------------------------------------------------------------------------
// Device-scope grid barrier (generation / sense-reversing).
// bar[0] = arrive count, bar[1] = generation. NO cooperative launch needed:
// LDS/block = 70656 B -> hard cap 2 blocks/CU -> 256 blocks always fit
// co-resident on 256 CUs (capacity 512), so the barrier cannot deadlock.
// Release via ACQ_REL fetch_add (after __syncthreads drained vmcnt, all the
// block's stores sit in this XCD's L2; the release flushes it). Acquire for
// the winner is the ACQ_REL RMW itself (last in atomic order); waiters do a
// relaxed spin (agent-scope atomic loads bypass L2 via sc1) + __threadfence.
// ---------------------------------------------------------------------------
__device__ __forceinline__ void gbar(unsigned* bar) {
    __syncthreads();
    if (threadIdx.x == 0) {
        unsigned g = __hip_atomic_load(bar + 1, __ATOMIC_RELAXED, __HIP_MEMORY_SCOPE_AGENT);
        unsigned a = __hip_atomic_fetch_add(bar, 1u, __ATOMIC_ACQ_REL, __HIP_MEMORY_SCOPE_AGENT);
        if (a == NBLK - 1u) {
            __hip_atomic_store(bar, 0u, __ATOMIC_RELAXED, __HIP_MEMORY_SCOPE_AGENT);
            __hip_atomic_store(bar + 1, g + 1u, __ATOMIC_RELEASE, __HIP_MEMORY_SCOPE_AGENT);
            __threadfence();   // belt-and-braces acquire for the winner
        } else {
            while (__hip_atomic_load(bar + 1, __ATOMIC_RELAXED, __HIP_MEMORY_SCOPE_AGENT) == g)
                __builtin_amdgcn_s_sleep(2);
            __threadfence();   // acquire: invalidate L1/L2 for whole block
        }
    }
    __syncthreads();
}

// ---------------------------------------------------------------------------
// Shared GEMM phase for recur/trans: C(256x2048,packed) = A_T^T @ Wp, K=512.
// Grid role: bid -> bm=(bid>>5)*32 rows, bn=(bid&31)*64 packed cols.
// 4 waves k-split the reduction (wave kg handles kk in [kg*16,kg*16+16) of
// each BK=64 tile); per-lane 4x8 microtile (r8=lane&7 -> rows r8*4..+3,
// c8=lane>>3 -> cols c8*8..+7); cross-wave sum via LDS; after reduction
// (wave,lane) owns row bm+r8*4+kg, cols bn+c8*8..+7 -> s[0..7].
// Staging: BK=64 tiles, register double-buffered (loads for tile t+1 issued
// during compute of tile t).
// ---------------------------------------------------------------------------
__device__ __forceinline__ void rt_gemm(
    const float* __restrict__ AT,   // [512][256] k-major (transposed activ.)
    const float* __restrict__ Wp,   // [512][2048] packed
    int bm, int bn, int tid,
    float (* __restrict__ As)[36], float (* __restrict__ Ws)[80],
    float* __restrict__ RedF,
    float* __restrict__ s, int& row_out)
{
    const int lane = tid & 63;
    const int kg = tid >> 6;          // wave = k-split group
    const int r8 = lane & 7;
    const int c8 = lane >> 3;
    const int akr = tid >> 3;         // A staging: k-row 0..31 (+32)
    const int amc = (tid & 7) * 4;    //            m-col
    const int wwr = tid >> 4;         // W staging: k-row 0..15 (+16/32/48)
    const int wwc = (tid & 15) * 4;   //            n-col

    const float* ap = AT + (size_t)akr * BB + bm + amc;
    const float* wp = Wp + (size_t)wwr * G4 + bn + wwc;

    float4 a0 = *(const float4*)ap;
    float4 a1 = *(const float4*)(ap + 32 * BB);
    float4 w0 = *(const float4*)wp;
    float4 w1 = *(const float4*)(wp + 16 * G4);
    float4 w2 = *(const float4*)(wp + 32 * G4);
    float4 w3 = *(const float4*)(wp + 48 * G4);

    float acc[4][8];
#pragma unroll
    for (int r = 0; r < 4; ++r)
#pragma unroll
        for (int j = 0; j < 8; ++j) acc[r][j] = 0.f;

#pragma unroll 1
    for (int tile = 0; tile < 8; ++tile) {
        __syncthreads();              // prev tile reads / prev phase LDS done
        *(float4*)&As[akr][amc] = a0;
        *(float4*)&As[akr + 32][amc] = a1;
        *(float4*)&Ws[wwr][wwc] = w0;
        *(float4*)&Ws[wwr + 16][wwc] = w1;
        *(float4*)&Ws[wwr + 32][wwc] = w2;
        *(float4*)&Ws[wwr + 48][wwc] = w3;
        if (tile < 7) {               // prefetch next tile into regs
            ap += 64 * BB;
            wp += 64 * G4;
            a0 = *(const float4*)ap;
            a1 = *(const float4*)(ap + 32 * BB);
            w0 = *(const float4*)wp;
            w1 = *(const float4*)(wp + 16 * G4);
            w2 = *(const float4*)(wp + 32 * G4);
            w3 = *(const float4*)(wp + 48 * G4);
        }
        __syncthreads();              // staged tile visible
        const int kb = kg * 16;
#pragma unroll
        for (int q = 0; q < 16; ++q) {
            float4 av4 = *(const float4*)&As[kb + q][r8 * 4];
            float4 wv0 = *(const float4*)&Ws[kb + q][c8 * 8];
            float4 wv1 = *(const float4*)&Ws[kb + q][c8 * 8 + 4];
            float av[4] = {av4.x, av4.y, av4.z, av4.w};
            float wv[8] = {wv0.x, wv0.y, wv0.z, wv0.w, wv1.x, wv1.y, wv1.z, wv1.w};
#pragma unroll
            for (int r = 0; r < 4; ++r)
#pragma unroll
                for (int j = 0; j < 8; ++j)
                    acc[r][j] += av[r] * wv[j];
        }
    }

    // cross-wave k reduction: Red[kg][i][lane], i = r*8+j (stride-64 lanes
    // -> conflict-free). Wave kg then owns output row r = kg.
#pragma unroll
    for (int r = 0; r < 4; ++r)
#pragma unroll
        for (int j = 0; j < 8; ++j)
            RedF[(kg * 32 + r * 8 + j) * 64 + lane] = acc[r][j];
    __syncthreads();
#pragma unroll
    for (int j = 0; j < 8; ++j)
        s[j] = RedF[(kg * 8 + j) * 64 + lane]
             + RedF[(32 + kg * 8 + j) * 64 + lane]
             + RedF[(64 + kg * 8 + j) * 64 + lane]
             + RedF[(96 + kg * 8 + j) * 64 + lane];
    row_out = bm + r8 * 4 + kg;
}

// ---------------------------------------------------------------------------
// xg phase: xg[t][m][n] = x[m][t][:] @ Wxg + bias0, M=256 K=256 N=2560.
// Same grid mapping, Ntile=80 (cols bnx..bnx+79), per-lane 4x(8+2) microtile
// (cols c8*8..+7 and 64+c8*2..+1 keep all LDS vector reads aligned).
// A (x) staged with scalar transpose-stores (only 4 tiles, cheap).
// ---------------------------------------------------------------------------
__device__ __forceinline__ void xg_phase(
    const float* __restrict__ x, const float* __restrict__ Wxg,
    const float* __restrict__ bias0, float* __restrict__ xgdst, int t,
    int bm, int bnx, int tid,
    float (* __restrict__ As)[36], float (* __restrict__ Ws)[80],
    float* __restrict__ RedF)
{
    const int lane = tid & 63;
    const int kg = tid >> 6;
    const int r8 = lane & 7;
    const int c8 = lane >> 3;
    const int xbr = tid >> 3;            // 0..31 batch row
    const int xdc = (tid & 7) * 8;       // 0..56 d base

    float acc[4][10];
#pragma unroll
    for (int r = 0; r < 4; ++r)
#pragma unroll
        for (int c = 0; c < 10; ++c) acc[r][c] = 0.f;

    const float* xrow = x + ((size_t)(bm + xbr) * TT + t) * DD;

#pragma unroll 1
    for (int tile = 0; tile < 4; ++tile) {
        const int k0 = tile * 64;
        float4 xa0 = *(const float4*)(xrow + k0 + xdc);
        float4 xa1 = *(const float4*)(xrow + k0 + xdc + 4);
        float4 wv[5];
#pragma unroll
        for (int l = 0; l < 5; ++l) {
            int idx = tid + l * 256;         // 0..1279 covers 64x80 / 4
            int wrow = idx / 20;
            int wcol = (idx % 20) * 4;
            wv[l] = *(const float4*)(Wxg + (size_t)(k0 + wrow) * G5 + bnx + wcol);
        }
        __syncthreads();
        As[xdc + 0][xbr] = xa0.x; As[xdc + 1][xbr] = xa0.y;
        As[xdc + 2][xbr] = xa0.z; As[xdc + 3][xbr] = xa0.w;
        As[xdc + 4][xbr] = xa1.x; As[xdc + 5][xbr] = xa1.y;
        As[xdc + 6][xbr] = xa1.z; As[xdc + 7][xbr] = xa1.w;
#pragma unroll
        for (int l = 0; l < 5; ++l) {
            int idx = tid + l * 256;
            int wrow = idx / 20;
            int wcol = (idx % 20) * 4;
            *(float4*)&Ws[wrow][wcol] = wv[l];
        }
        __syncthreads();
        const int kb = kg * 16;
#pragma unroll
        for (int q = 0; q < 16; ++q) {
            float4 av4 = *(const float4*)&As[kb + q][r8 * 4];
            float4 wv0 = *(const float4*)&Ws[kb + q][c8 * 8];
            float4 wv1 = *(const float4*)&Ws[kb + q][c8 * 8 + 4];
            float2 wv2 = *(const float2*)&Ws[kb + q][64 + c8 * 2];
            float av[4] = {av4.x, av4.y, av4.z, av4.w};
            float wvv[10] = {wv0.x, wv0.y, wv0.z, wv0.w,
                             wv1.x, wv1.y, wv1.z, wv1.w, wv2.x, wv2.y};
#pragma unroll
            for (int r = 0; r < 4; ++r)
#pragma unroll
                for (int c = 0; c < 10; ++c)
                    acc[r][c] += av[r] * wvv[c];
        }
    }

#pragma unroll
    for (int r = 0; r < 4; ++r)
#pragma unroll
        for (int c = 0; c < 10; ++c)
            RedF[(kg * 40 + r * 10 + c) * 64 + lane] = acc[r][c];
    __syncthreads();
    const int row = bm + r8 * 4 + kg;
#pragma unroll
    for (int c = 0; c < 10; ++c) {
        float sv = RedF[(kg * 10 + c) * 64 + lane]
                 + RedF[(40 + kg * 10 + c) * 64 + lane]
                 + RedF[(80 + kg * 10 + c) * 64 + lane]
                 + RedF[(120 + kg * 10 + c) * 64 + lane];
        int n = bnx + (c < 8 ? c8 * 8 + c : 64 + c8 * 2 + (c - 8));
        xgdst[(size_t)row * G5 + n] = sv + bias0[n];
    }
}

// ---------------------------------------------------------------------------
// Persistent scan kernel: 256 blocks (1/CU) x 256 threads, plain launch.
// Per step: R -> bar -> T0 (+xg(t+1)) -> bar -> T1(final) -> bar.
// ---------------------------------------------------------------------------
__global__ __launch_bounds__(256, 1) void scan_all(
    const float* __restrict__ x,
    const float* __restrict__ Wxg,
    const float* __restrict__ rkp,
    const float* __restrict__ tkp0,
    const float* __restrict__ tkp1,
    const float* __restrict__ bias,
    const float* __restrict__ tb,
    float* hT, float* h1aT, float* h1bT, float* prl,
    float* xg0, float* xg1, float* out, unsigned* bar)
{
    __shared__ float As[64][36];      // [k][m], pad->36 keeps b128 aligned
    __shared__ float Ws[64][80];      // [k][n] (RT uses 64 cols, XG 80)
    __shared__ float RedF[10240];     // cross-wave reduction scratch (40 KB)

    const int tid = threadIdx.x;
    const int bid = blockIdx.x;
    const int bm = (bid >> 5) * 32;
    const int bn = (bid & 31) * 64;
    const int bnx = (bid & 31) * 80;
    const int lane = tid & 63;
    const int c8 = lane >> 3;
    const int ub = (bn >> 2) + c8 * 2;   // base u for this lane (2 u's)

    const float* bias0 = bias;
    const float* bias1 = bias + G5;
    const float* tb0 = tb;
    const float* tb1 = tb + 3 * UU;

    // xg for t=0
    xg_phase(x, Wxg, bias0, xg0, 0, bm, bnx, tid, As, Ws, RedF);
    gbar(bar);

    float* xgc = xg0;
    float* xgn = xg1;

    for (int t = 0; t < TT; ++t) {
        // ---- R: hg = h @ rkp ; gates -> h1a, pre_l ----
        {
            float s[8]; int row;
            rt_gemm(hT, rkp, bm, bn, tid, As, Ws, RedF, s, row);
            const float* xr_ = xgc + (size_t)row * G5;
#pragma unroll
            for (int uu = 0; uu < 2; ++uu) {
                int u = ub + uu;
                float z  = hsig(xr_[u] + s[uu * 4 + 0] + bias1[u]);
                float r  = hsig(xr_[UU + u] + s[uu * 4 + 1] + bias1[UU + u]);
                float hh = tanhf(xr_[2 * UU + u] + r * (s[uu * 4 + 2] + bias1[2 * UU + u]));
                float hold = hT[(size_t)u * BB + row];
                h1aT[(size_t)u * BB + row] = z * hold + (1.f - z) * hh;
                prl[(size_t)row * UU + u] = xr_[3 * UU + u] + s[uu * 4 + 3] + bias1[3 * UU + u];
            }
        }
        gbar(bar);

        // ---- T0: tg = h1a @ tkp0 ; gates -> h1b ; plus xg(t+1) ----
        {
            float s[8]; int row;
            rt_gemm(h1aT, tkp0, bm, bn, tid, As, Ws, RedF, s, row);
#pragma unroll
            for (int uu = 0; uu < 2; ++uu) {
                int u = ub + uu;
                float zt = hsig(s[uu * 4 + 0] + tb0[u]);
                float rt = hsig(s[uu * 4 + 1] + tb0[UU + u]);
                float ht = tanhf(rt * (s[uu * 4 + 2] + tb0[2 * UU + u]));
                float h1v = h1aT[(size_t)u * BB + row];
                h1bT[(size_t)u * BB + row] = zt * h1v + (1.f - zt) * ht;
            }
        }
        if (t + 1 < TT)
            xg_phase(x, Wxg, bias0, xgn, t + 1, bm, bnx, tid, As, Ws, RedF);
        gbar(bar);

        // ---- T1 (final): tg = h1b @ tkp1 ; gates + output gate -> h, out ----
        {
            float s[8]; int row;
            rt_gemm(h1bT, tkp1, bm, bn, tid, As, Ws, RedF, s, row);
#pragma unroll
            for (int uu = 0; uu < 2; ++uu) {
                int u = ub + uu;
                float zt = hsig(s[uu * 4 + 0] + tb1[u]);
                float rt = hsig(s[uu * 4 + 1] + tb1[UU + u]);
                float ht = tanhf(rt * (s[uu * 4 + 2] + tb1[2 * UU + u]));
                float h1v = h1bT[(size_t)u * BB + row];
                float h2 = zt * h1v + (1.f - zt) * ht;
                float l = hsig(prl[(size_t)row * UU + u]);
                float xl2 = xgc[(size_t)row * G5 + 4 * UU + u];
                float ho = l * h2 + (1.f - l) * tanhf(xl2);
                hT[(size_t)u * BB + row] = ho;
                out[((size_t)row * TT + t) * UU + u] = ho;
            }
        }
        gbar(bar);

        float* tmp = xgc; xgc = xgn; xgn = tmp;
    }
}

extern "C" void kernel_launch(void* const* d_in, const int* in_sizes, int n_in,
                              void* d_out, int out_size, void* d_ws, size_t ws_size,
                              hipStream_t stream) {
    const float* x      = (const float*)d_in[0];  // (B,T,D)
    const float* h0     = (const float*)d_in[1];  // (B,U)
    const float* kernel = (const float*)d_in[2];  // (D,5U)
    const float* rk     = (const float*)d_in[3];  // (U,4U)
    const float* tk     = (const float*)d_in[4];  // (2,U,3U)
    const float* bias   = (const float*)d_in[5];  // (2,5U)
    const float* tb     = (const float*)d_in[6];  // (2,3U)
    float* out = (float*)d_out;

    // workspace layout (floats); bar occupies first 256 B
    unsigned* bar = (unsigned*)d_ws;
    float* base = (float*)d_ws + 64;
    float* rkp  = base;                               // 512*2048
    float* tkp0 = rkp  + (size_t)UU * G4;             // 512*2048
    float* tkp1 = tkp0 + (size_t)UU * G4;             // 512*2048
    float* hT   = tkp1 + (size_t)UU * G4;             // U*B (transposed state)
    float* h1aT = hT   + (size_t)BB * UU;
    float* h1bT = h1aT + (size_t)BB * UU;
    float* prl  = h1bT + (size_t)BB * UU;
    float* xg0  = prl  + (size_t)BB * UU;             // B*5U
    float* xg1  = xg0  + (size_t)BB * G5;             // B*5U
    // total = 64 + 3*1048576 + 4*131072 + 2*655360 floats ~= 19.9 MB

    hipMemsetAsync(d_ws, 0, 256, stream);   // zero barrier state
    pack_weights<<<dim3((UU * G4) / 256), dim3(256), 0, stream>>>(rk, tk, rkp, tkp0, tkp1);
    init_hT<<<dim3((BB * UU) / 256), dim3(256), 0, stream>>>(h0, hT);

    // Plain launch (graph-capture safe). Residency guaranteed by capacity:
    // 70656 B LDS/block -> <=2 blocks/CU, 256 blocks <= 256 CUs * 2.
    scan_all<<<dim3(NBLK), dim3(256), 0, stream>>>(
        x, kernel, rkp, tkp0, tkp1, bias, tb,
        hT, h1aT, h1bT, prl, xg0, xg1, out, bar);
}

// Round 3
// 8507.476 us; speedup vs baseline: 2.1941x; 2.1941x over previous
//
#include <hip/hip_runtime.h>
#include <math.h>

#define BB 256   // batch
#define TT 128   // time steps
#define DD 256   // input dim
#define UU 512   // units
#define G5 (5 * UU)   // 2560
#define G4 (4 * UU)   // 2048 (packed width for rk and tk)
#define NBLK 256
#define GBLK 32       // blocks per barrier group (same bm)

__device__ __forceinline__ float hsig(float x) {
    return fminf(fmaxf(0.2f * x + 0.5f, 0.0f), 1.0f);
}

// Agent-visible store: relaxed agent-scope atomic -> global_store with sc1,
// bypassing the (non-coherent) XCD L2. After vmcnt drain the value is at LLC,
// so barrier release needs NO buffer_wbl2 (the 18.8ms kernel's killer: every
// ACQ_REL RMW / threadfence emitted a full L2 dirty-writeback walk -> 1.5 GB
// WRITE_SIZE for 67 MB of output).
__device__ __forceinline__ void st_agent(float* p, float v) {
    __hip_atomic_store(p, v, __ATOMIC_RELAXED, __HIP_MEMORY_SCOPE_AGENT);
}

// ---------------------------------------------------------------------------
// Pack weights into gate-interleaved layout: col = u*4 + g   (verified layout)
// ---------------------------------------------------------------------------
__global__ __launch_bounds__(256) void pack_weights(
    const float* __restrict__ rk, const float* __restrict__ tk,
    float* __restrict__ rkp, float* __restrict__ tkp0, float* __restrict__ tkp1)
{
    int idx = blockIdx.x * 256 + threadIdx.x;   // 0 .. 512*2048
    int k = idx >> 11;
    int c = idx & 2047;
    int u = c >> 2;
    int g = c & 3;
    rkp[idx] = rk[k * G4 + g * UU + u];
    float t0 = 0.f, t1 = 0.f;
    if (g < 3) {
        t0 = tk[(size_t)k * (3 * UU) + g * UU + u];
        t1 = tk[(size_t)(UU + k) * (3 * UU) + g * UU + u];
    }
    tkp0[idx] = t0;
    tkp1[idx] = t1;
}

// h state kept transposed: hT[u][b]  (u-major) so GEMM A-staging is coalesced
__global__ __launch_bounds__(256) void init_hT(
    const float* __restrict__ h0, float* __restrict__ hT)
{
    int idx = blockIdx.x * 256 + threadIdx.x;   // 0 .. 131071
    int u = idx >> 8;
    int b = idx & 255;
    hT[idx] = h0[(size_t)b * UU + u];
}

// ---------------------------------------------------------------------------
// Group-local monotonic barrier (32 blocks sharing the same bm — the batch
// dimension fully decomposes: block (bm,bn) only communicates with blocks of
// the same bm). Monotonic count: arrive = relaxed fetch_add(1); wait until
// count >= phase*GBLK. No generation reset -> no store-ordering hazard, and
// all atomics are RELAXED (sc1, LLC-direct: no wbl2 anywhere). Acquire =
// one buffer_inv per block (fence acquire agent) so post-barrier plain loads
// refetch fresh LLC data. Data was published with st_agent; __syncthreads
// drains each wave's vmcnt before thread0 signals.
// ---------------------------------------------------------------------------
__device__ __forceinline__ void gbar(unsigned* cnt, unsigned& phase) {
    __syncthreads();
    if (threadIdx.x == 0) {
        phase += GBLK;
        __hip_atomic_fetch_add(cnt, 1u, __ATOMIC_RELAXED, __HIP_MEMORY_SCOPE_AGENT);
        while ((int)(__hip_atomic_load(cnt, __ATOMIC_RELAXED, __HIP_MEMORY_SCOPE_AGENT) - phase) < 0)
            __builtin_amdgcn_s_sleep(2);
        __builtin_amdgcn_fence(__ATOMIC_ACQUIRE, "agent");   // buffer_inv only
    }
    __syncthreads();
}

// ---------------------------------------------------------------------------
// Shared GEMM phase for recur/trans: C(256x2048,packed) = A_T^T @ Wp, K=512.
// bid -> bm=(bid>>5)*32 rows, bn=(bid&31)*64 packed cols. 4 waves k-split;
// per-lane 4x8 microtile; cross-wave sum via LDS; (wave,lane) owns row
// bm+r8*4+kg, cols bn+c8*8..+7. BK=64 tiles, register double-buffered.
// ---------------------------------------------------------------------------
__device__ __forceinline__ void rt_gemm(
    const float* __restrict__ AT,   // [512][256] k-major (transposed activ.)
    const float* __restrict__ Wp,   // [512][2048] packed
    int bm, int bn, int tid,
    float (* __restrict__ As)[36], float (* __restrict__ Ws)[80],
    float* __restrict__ RedF,
    float* __restrict__ s, int& row_out)
{
    const int lane = tid & 63;
    const int kg = tid >> 6;          // wave = k-split group
    const int r8 = lane & 7;
    const int c8 = lane >> 3;
    const int akr = tid >> 3;         // A staging: k-row 0..31 (+32)
    const int amc = (tid & 7) * 4;    //            m-col
    const int wwr = tid >> 4;         // W staging: k-row 0..15 (+16/32/48)
    const int wwc = (tid & 15) * 4;   //            n-col

    const float* ap = AT + (size_t)akr * BB + bm + amc;
    const float* wp = Wp + (size_t)wwr * G4 + bn + wwc;

    float4 a0 = *(const float4*)ap;
    float4 a1 = *(const float4*)(ap + 32 * BB);
    float4 w0 = *(const float4*)wp;
    float4 w1 = *(const float4*)(wp + 16 * G4);
    float4 w2 = *(const float4*)(wp + 32 * G4);
    float4 w3 = *(const float4*)(wp + 48 * G4);

    float acc[4][8];
#pragma unroll
    for (int r = 0; r < 4; ++r)
#pragma unroll
        for (int j = 0; j < 8; ++j) acc[r][j] = 0.f;

#pragma unroll 1
    for (int tile = 0; tile < 8; ++tile) {
        __syncthreads();              // prev tile reads / prev phase LDS done
        *(float4*)&As[akr][amc] = a0;
        *(float4*)&As[akr + 32][amc] = a1;
        *(float4*)&Ws[wwr][wwc] = w0;
        *(float4*)&Ws[wwr + 16][wwc] = w1;
        *(float4*)&Ws[wwr + 32][wwc] = w2;
        *(float4*)&Ws[wwr + 48][wwc] = w3;
        if (tile < 7) {               // prefetch next tile into regs
            ap += 64 * BB;
            wp += 64 * G4;
            a0 = *(const float4*)ap;
            a1 = *(const float4*)(ap + 32 * BB);
            w0 = *(const float4*)wp;
            w1 = *(const float4*)(wp + 16 * G4);
            w2 = *(const float4*)(wp + 32 * G4);
            w3 = *(const float4*)(wp + 48 * G4);
        }
        __syncthreads();              // staged tile visible
        const int kb = kg * 16;
#pragma unroll
        for (int q = 0; q < 16; ++q) {
            float4 av4 = *(const float4*)&As[kb + q][r8 * 4];
            float4 wv0 = *(const float4*)&Ws[kb + q][c8 * 8];
            float4 wv1 = *(const float4*)&Ws[kb + q][c8 * 8 + 4];
            float av[4] = {av4.x, av4.y, av4.z, av4.w};
            float wv[8] = {wv0.x, wv0.y, wv0.z, wv0.w, wv1.x, wv1.y, wv1.z, wv1.w};
#pragma unroll
            for (int r = 0; r < 4; ++r)
#pragma unroll
                for (int j = 0; j < 8; ++j)
                    acc[r][j] += av[r] * wv[j];
        }
    }

    // cross-wave k reduction (stride-64 lanes -> conflict-free)
#pragma unroll
    for (int r = 0; r < 4; ++r)
#pragma unroll
        for (int j = 0; j < 8; ++j)
            RedF[(kg * 32 + r * 8 + j) * 64 + lane] = acc[r][j];
    __syncthreads();
#pragma unroll
    for (int j = 0; j < 8; ++j)
        s[j] = RedF[(kg * 8 + j) * 64 + lane]
             + RedF[(32 + kg * 8 + j) * 64 + lane]
             + RedF[(64 + kg * 8 + j) * 64 + lane]
             + RedF[(96 + kg * 8 + j) * 64 + lane];
    row_out = bm + r8 * 4 + kg;
}

// ---------------------------------------------------------------------------
// xg phase: xg[t][m][n] = x[m][t][:] @ Wxg + bias0, M=256 K=256 N=2560.
// Ntile=80, per-lane 4x(8+2) microtile.
// ---------------------------------------------------------------------------
__device__ __forceinline__ void xg_phase(
    const float* __restrict__ x, const float* __restrict__ Wxg,
    const float* __restrict__ bias0, float* __restrict__ xgdst, int t,
    int bm, int bnx, int tid,
    float (* __restrict__ As)[36], float (* __restrict__ Ws)[80],
    float* __restrict__ RedF)
{
    const int lane = tid & 63;
    const int kg = tid >> 6;
    const int r8 = lane & 7;
    const int c8 = lane >> 3;
    const int xbr = tid >> 3;            // 0..31 batch row
    const int xdc = (tid & 7) * 8;       // 0..56 d base

    float acc[4][10];
#pragma unroll
    for (int r = 0; r < 4; ++r)
#pragma unroll
        for (int c = 0; c < 10; ++c) acc[r][c] = 0.f;

    const float* xrow = x + ((size_t)(bm + xbr) * TT + t) * DD;

#pragma unroll 1
    for (int tile = 0; tile < 4; ++tile) {
        const int k0 = tile * 64;
        float4 xa0 = *(const float4*)(xrow + k0 + xdc);
        float4 xa1 = *(const float4*)(xrow + k0 + xdc + 4);
        float4 wv[5];
#pragma unroll
        for (int l = 0; l < 5; ++l) {
            int idx = tid + l * 256;         // 0..1279 covers 64x80 / 4
            int wrow = idx / 20;
            int wcol = (idx % 20) * 4;
            wv[l] = *(const float4*)(Wxg + (size_t)(k0 + wrow) * G5 + bnx + wcol);
        }
        __syncthreads();
        As[xdc + 0][xbr] = xa0.x; As[xdc + 1][xbr] = xa0.y;
        As[xdc + 2][xbr] = xa0.z; As[xdc + 3][xbr] = xa0.w;
        As[xdc + 4][xbr] = xa1.x; As[xdc + 5][xbr] = xa1.y;
        As[xdc + 6][xbr] = xa1.z; As[xdc + 7][xbr] = xa1.w;
#pragma unroll
        for (int l = 0; l < 5; ++l) {
            int idx = tid + l * 256;
            int wrow = idx / 20;
            int wcol = (idx % 20) * 4;
            *(float4*)&Ws[wrow][wcol] = wv[l];
        }
        __syncthreads();
        const int kb = kg * 16;
#pragma unroll
        for (int q = 0; q < 16; ++q) {
            float4 av4 = *(const float4*)&As[kb + q][r8 * 4];
            float4 wv0 = *(const float4*)&Ws[kb + q][c8 * 8];
            float4 wv1 = *(const float4*)&Ws[kb + q][c8 * 8 + 4];
            float2 wv2 = *(const float2*)&Ws[kb + q][64 + c8 * 2];
            float av[4] = {av4.x, av4.y, av4.z, av4.w};
            float wvv[10] = {wv0.x, wv0.y, wv0.z, wv0.w,
                             wv1.x, wv1.y, wv1.z, wv1.w, wv2.x, wv2.y};
#pragma unroll
            for (int r = 0; r < 4; ++r)
#pragma unroll
                for (int c = 0; c < 10; ++c)
                    acc[r][c] += av[r] * wvv[c];
        }
    }

#pragma unroll
    for (int r = 0; r < 4; ++r)
#pragma unroll
        for (int c = 0; c < 10; ++c)
            RedF[(kg * 40 + r * 10 + c) * 64 + lane] = acc[r][c];
    __syncthreads();
    const int row = bm + r8 * 4 + kg;
#pragma unroll
    for (int c = 0; c < 10; ++c) {
        float sv = RedF[(kg * 10 + c) * 64 + lane]
                 + RedF[(40 + kg * 10 + c) * 64 + lane]
                 + RedF[(80 + kg * 10 + c) * 64 + lane]
                 + RedF[(120 + kg * 10 + c) * 64 + lane];
        int n = bnx + (c < 8 ? c8 * 8 + c : 64 + c8 * 2 + (c - 8));
        st_agent(&xgdst[(size_t)row * G5 + n], sv + bias0[n]);
    }
}

// ---------------------------------------------------------------------------
// Persistent scan kernel: 256 blocks (1/CU) x 256 threads, plain launch.
// Per step: R -> gbar -> T0 (+xg(t+1)) -> gbar -> T1(final) -> gbar.
// Barriers are GROUP-LOCAL (32 blocks sharing bm).
// ---------------------------------------------------------------------------
__global__ __launch_bounds__(256, 1) void scan_all(
    const float* __restrict__ x,
    const float* __restrict__ Wxg,
    const float* __restrict__ rkp,
    const float* __restrict__ tkp0,
    const float* __restrict__ tkp1,
    const float* __restrict__ bias,
    const float* __restrict__ tb,
    float* hT, float* h1aT, float* h1bT, float* prl,
    float* xg0, float* xg1, float* out, unsigned* bar)
{
    __shared__ float As[64][36];      // [k][m], pad->36 keeps b128 aligned
    __shared__ float Ws[64][80];      // [k][n] (RT uses 64 cols, XG 80)
    __shared__ float RedF[10240];     // cross-wave reduction scratch (40 KB)

    const int tid = threadIdx.x;
    const int bid = blockIdx.x;
    const int bm = (bid >> 5) * 32;
    const int bn = (bid & 31) * 64;
    const int bnx = (bid & 31) * 80;
    const int lane = tid & 63;
    const int c8 = lane >> 3;
    const int ub = (bn >> 2) + c8 * 2;   // base u for this lane (2 u's)

    unsigned* cnt = bar + (bid >> 5) * 32;   // group counter, 128B apart
    unsigned phase = 0;

    const float* bias0 = bias;
    const float* bias1 = bias + G5;
    const float* tb0 = tb;
    const float* tb1 = tb + 3 * UU;

    // xg for t=0
    xg_phase(x, Wxg, bias0, xg0, 0, bm, bnx, tid, As, Ws, RedF);
    gbar(cnt, phase);

    float* xgc = xg0;
    float* xgn = xg1;

    for (int t = 0; t < TT; ++t) {
        // ---- R: hg = h @ rkp ; gates -> h1a, pre_l ----
        {
            float s[8]; int row;
            rt_gemm(hT, rkp, bm, bn, tid, As, Ws, RedF, s, row);
            const float* xr_ = xgc + (size_t)row * G5;
#pragma unroll
            for (int uu = 0; uu < 2; ++uu) {
                int u = ub + uu;
                float z  = hsig(xr_[u] + s[uu * 4 + 0] + bias1[u]);
                float r  = hsig(xr_[UU + u] + s[uu * 4 + 1] + bias1[UU + u]);
                float hh = tanhf(xr_[2 * UU + u] + r * (s[uu * 4 + 2] + bias1[2 * UU + u]));
                float hold = hT[(size_t)u * BB + row];
                st_agent(&h1aT[(size_t)u * BB + row], z * hold + (1.f - z) * hh);
                st_agent(&prl[(size_t)row * UU + u],
                         xr_[3 * UU + u] + s[uu * 4 + 3] + bias1[3 * UU + u]);
            }
        }
        gbar(cnt, phase);

        // ---- T0: tg = h1a @ tkp0 ; gates -> h1b ; plus xg(t+1) ----
        {
            float s[8]; int row;
            rt_gemm(h1aT, tkp0, bm, bn, tid, As, Ws, RedF, s, row);
#pragma unroll
            for (int uu = 0; uu < 2; ++uu) {
                int u = ub + uu;
                float zt = hsig(s[uu * 4 + 0] + tb0[u]);
                float rt = hsig(s[uu * 4 + 1] + tb0[UU + u]);
                float ht = tanhf(rt * (s[uu * 4 + 2] + tb0[2 * UU + u]));
                float h1v = h1aT[(size_t)u * BB + row];
                st_agent(&h1bT[(size_t)u * BB + row], zt * h1v + (1.f - zt) * ht);
            }
        }
        if (t + 1 < TT)
            xg_phase(x, Wxg, bias0, xgn, t + 1, bm, bnx, tid, As, Ws, RedF);
        gbar(cnt, phase);

        // ---- T1 (final): tg = h1b @ tkp1 ; gates + output gate -> h, out ----
        {
            float s[8]; int row;
            rt_gemm(h1bT, tkp1, bm, bn, tid, As, Ws, RedF, s, row);
#pragma unroll
            for (int uu = 0; uu < 2; ++uu) {
                int u = ub + uu;
                float zt = hsig(s[uu * 4 + 0] + tb1[u]);
                float rt = hsig(s[uu * 4 + 1] + tb1[UU + u]);
                float ht = tanhf(rt * (s[uu * 4 + 2] + tb1[2 * UU + u]));
                float h1v = h1bT[(size_t)u * BB + row];
                float h2 = zt * h1v + (1.f - zt) * ht;
                float l = hsig(prl[(size_t)row * UU + u]);
                float xl2 = xgc[(size_t)row * G5 + 4 * UU + u];
                float ho = l * h2 + (1.f - l) * tanhf(xl2);
                st_agent(&hT[(size_t)u * BB + row], ho);
                out[((size_t)row * TT + t) * UU + u] = ho;   // host-read only
            }
        }
        gbar(cnt, phase);

        float* tmp = xgc; xgc = xgn; xgn = tmp;
    }
}

extern "C" void kernel_launch(void* const* d_in, const int* in_sizes, int n_in,
                              void* d_out, int out_size, void* d_ws, size_t ws_size,
                              hipStream_t stream) {
    const float* x      = (const float*)d_in[0];  // (B,T,D)
    const float* h0     = (const float*)d_in[1];  // (B,U)
    const float* kernel = (const float*)d_in[2];  // (D,5U)
    const float* rk     = (const float*)d_in[3];  // (U,4U)
    const float* tk     = (const float*)d_in[4];  // (2,U,3U)
    const float* bias   = (const float*)d_in[5];  // (2,5U)
    const float* tb     = (const float*)d_in[6];  // (2,3U)
    float* out = (float*)d_out;

    // workspace layout (floats); barrier counters occupy first 1024 B
    unsigned* bar = (unsigned*)d_ws;
    float* base = (float*)d_ws + 256;
    float* rkp  = base;                               // 512*2048
    float* tkp0 = rkp  + (size_t)UU * G4;             // 512*2048
    float* tkp1 = tkp0 + (size_t)UU * G4;             // 512*2048
    float* hT   = tkp1 + (size_t)UU * G4;             // U*B (transposed state)
    float* h1aT = hT   + (size_t)BB * UU;
    float* h1bT = h1aT + (size_t)BB * UU;
    float* prl  = h1bT + (size_t)BB * UU;
    float* xg0  = prl  + (size_t)BB * UU;             // B*5U
    float* xg1  = xg0  + (size_t)BB * G5;             // B*5U

    hipMemsetAsync(d_ws, 0, 1024, stream);   // zero barrier counters
    pack_weights<<<dim3((UU * G4) / 256), dim3(256), 0, stream>>>(rk, tk, rkp, tkp0, tkp1);
    init_hT<<<dim3((BB * UU) / 256), dim3(256), 0, stream>>>(h0, hT);

    // Plain launch (graph-capture safe). Residency guaranteed by capacity:
    // 70656 B LDS/block -> <=2 blocks/CU, 256 blocks <= 256 CUs * 2.
    scan_all<<<dim3(NBLK), dim3(256), 0, stream>>>(
        x, kernel, rkp, tkp0, tkp1, bias, tb,
        hT, h1aT, h1bT, prl, xg0, xg1, out, bar);
}